// Round 2
// baseline (226.237 us; speedup 1.0000x reference)
//
#include <hip/hip_runtime.h>
#include <stdint.h>

// CSSA: B=32, H=W=64, C=64, heads=4, hd=16, strip windows 64x8 -> 256 windows.
// All tensors are FLOAT32 (reference dtype). MFMA inputs converted f32->bf16 (RNE),
// accumulation fp32 -> error ~0.02 abs vs threshold 0.05.
#define NB    32
#define CCH   64
#define HD    16
#define WIN   512
// LDS strides in bf16 elems (+8 pad -> 2-way bank alias on b128 reads = free)
#define KSTR  72
#define VSTR  520
#define PSTR  40

typedef __attribute__((ext_vector_type(8))) short          short8;  // MFMA A/B frag (8 bf16)
typedef __attribute__((ext_vector_type(4))) float          f32x4;   // MFMA C/D frag
typedef __attribute__((ext_vector_type(4))) unsigned short us4;

__device__ __forceinline__ float bf2f(unsigned short u) {
    union { unsigned int i; float f; } x; x.i = ((unsigned int)u) << 16; return x.f;
}
__device__ __forceinline__ unsigned short f2bf(float f) {
    union { float f; unsigned int i; } x; x.f = f;
    unsigned int r = x.i + 0x7FFFu + ((x.i >> 16) & 1u);   // RNE
    return (unsigned short)(r >> 16);
}

__global__ __launch_bounds__(512, 2)
void CSSA_69355131896243_kernel(const float* __restrict__ qkv,
                                const float* __restrict__ wconv,
                                const float* __restrict__ bconv,
                                float* __restrict__ out)
{
    __shared__ unsigned short Kl[WIN * KSTR];        // 73728 B  K: [token][ch] (bf16)
    __shared__ unsigned short Vt[CCH * VSTR];        // 66560 B  V^T: [ch][token] (bf16)
    __shared__ unsigned short Pl[8 * 16 * PSTR];     // 10240 B  per-wave P bounce

    const int tid  = threadIdx.x;
    const int wave = tid >> 6;
    const int lane = tid & 63;
    const int quad = lane >> 4;
    const int l15  = lane & 15;

    const int win = blockIdx.x;          // 0..255
    const int b   = win >> 3;
    const int wx  = win & 7;

    const size_t ONE  = (size_t)NB * 4096 * CCH;                 // one of q/k/v
    const size_t base = ((size_t)b * 4096 + (size_t)wx * 8) * CCH;

    // ---- stage K (natural) and V (transposed) into LDS as bf16; f32x4 global loads ----
    {
        const float* gK = qkv + ONE     + base;
        const float* gV = qkv + 2 * ONE + base;
        const int tokb = lane >> 4;            // (lane*4)>>6
        const int c0   = (lane & 15) * 4;      // 4-channel group
        for (int r = 0; r < 8; ++r) {
            const int y = r * 8 + wave;
            #pragma unroll
            for (int half = 0; half < 2; ++half) {
                const int t = y * 8 + half * 4 + tokb;
                const size_t goff = (size_t)y * 4096 + half * 256 + lane * 4;
                f32x4 kd = *(const f32x4*)(gK + goff);
                f32x4 vd = *(const f32x4*)(gV + goff);
                us4 kb;
                #pragma unroll
                for (int j = 0; j < 4; ++j) kb[j] = f2bf(kd[j]);
                *(us4*)(&Kl[t * KSTR + c0]) = kb;
                #pragma unroll
                for (int j = 0; j < 4; ++j) Vt[(c0 + j) * VSTR + t] = f2bf(vd[j]);
            }
        }
    }
    __syncthreads();

    // wave -> (head, query half)
    const int h  = wave >> 1;
    const int qh = wave & 1;
    const int ch = h * HD + l15;            // this lane's channel (d = l15)

    // LePE weights for this lane's channel (f32, exact)
    float wr[9];
    #pragma unroll
    for (int i = 0; i < 9; ++i) wr[i] = wconv[ch * 9 + i];
    const float bias = bconv[ch];

    unsigned short* Pw = &Pl[wave * 16 * PSTR];
    const float* gQ = qkv + base;
    const float EC = 0.25f * 1.44269504088896341f;   // scale * log2(e)

    for (int pass = 0; pass < 2; ++pass) {
        const int q0 = qh * 256 + pass * 128;

        // Q fragments: A[m=l15][k=quad*8+j]; quads 2,3 are K-padding (zeros)
        short8 qf[8];
        #pragma unroll
        for (int t = 0; t < 8; ++t) {
            if (quad < 2) {
                const int q = q0 + t * 16 + l15;
                const float* p = gQ + ((size_t)(q >> 3) * 64 + (q & 7)) * CCH + h * HD + quad * 8;
                f32x4 a = *(const f32x4*)p;
                f32x4 c = *(const f32x4*)(p + 4);
                short8 f;
                #pragma unroll
                for (int j = 0; j < 4; ++j) {
                    f[j]     = (short)f2bf(a[j]);
                    f[j + 4] = (short)f2bf(c[j]);
                }
                qf[t] = f;
            } else {
                qf[t] = (short8)0;
            }
        }

        f32x4 acc[8];
        f32x4 lp[8];
        #pragma unroll
        for (int t = 0; t < 8; ++t) { acc[t] = (f32x4)0.0f; lp[t] = (f32x4)0.0f; }

        for (int c = 0; c < 16; ++c) {         // 32-key chunks
            const int k0 = c * 32;
            short8 kf0 = (short8)0, kf1 = (short8)0;
            if (quad < 2) {   // B[k=d=quad*8+j][n=key=l15]; d>=16 zero padding
                kf0 = *(const short8*)(&Kl[(k0 + l15)      * KSTR + h * HD + quad * 8]);
                kf1 = *(const short8*)(&Kl[(k0 + 16 + l15) * KSTR + h * HD + quad * 8]);
            }
            // V frag: B[k=key=quad*8+j][n=d=l15] from V^T rows (contiguous)
            const short8 vf = *(const short8*)(&Vt[ch * VSTR + k0 + quad * 8]);

            #pragma unroll
            for (int t = 0; t < 8; ++t) {
                f32x4 s0 = __builtin_amdgcn_mfma_f32_16x16x32_bf16(qf[t], kf0, (f32x4)0.0f, 0, 0, 0);
                f32x4 s1 = __builtin_amdgcn_mfma_f32_16x16x32_bf16(qf[t], kf1, (f32x4)0.0f, 0, 0, 0);
                float p0[4], p1[4];
                #pragma unroll
                for (int j = 0; j < 4; ++j) {
                    p0[j] = __builtin_amdgcn_exp2f(s0[j] * EC);   // no-max softmax: fp32 exp safe
                    p1[j] = __builtin_amdgcn_exp2f(s1[j] * EC);
                    lp[t][j] += p0[j] + p1[j];                    // per-lane column partial
                }
                // C-layout -> A-layout bounce (per-wave private; in-order DS pipe)
                #pragma unroll
                for (int j = 0; j < 4; ++j) {
                    Pw[(quad * 4 + j) * PSTR + l15]      = f2bf(p0[j]);
                    Pw[(quad * 4 + j) * PSTR + 16 + l15] = f2bf(p1[j]);
                }
                const short8 pf = *(const short8*)(&Pw[l15 * PSTR + quad * 8]);
                acc[t] = __builtin_amdgcn_mfma_f32_16x16x32_bf16(pf, vf, acc[t], 0, 0, 0);
            }
        }

        // epilogue: denominator reduce, LePE from resident V^T, store f32
        #pragma unroll
        for (int t = 0; t < 8; ++t) {
            f32x4 l4 = lp[t];
            #pragma unroll
            for (int j = 0; j < 4; ++j) {
                float v = l4[j];
                v += __shfl_xor(v, 1, 64);
                v += __shfl_xor(v, 2, 64);
                v += __shfl_xor(v, 4, 64);
                v += __shfl_xor(v, 8, 64);
                l4[j] = __builtin_amdgcn_rcpf(v);
            }
            #pragma unroll
            for (int j = 0; j < 4; ++j) {
                const int q  = q0 + t * 16 + quad * 4 + j;
                const int y  = q >> 3;
                const int xp = q & 7;
                float lep = bias;
                #pragma unroll
                for (int dy = 0; dy < 3; ++dy) {
                    #pragma unroll
                    for (int dx = 0; dx < 3; ++dx) {
                        const int yy = y + dy - 1, xx = xp + dx - 1;
                        const bool ok = ((unsigned)yy < 64u) && ((unsigned)xx < 8u);
                        const int tt = (q + (dy - 1) * 8 + (dx - 1)) & 511;  // window-local, pad via mask
                        const float vv = bf2f(Vt[ch * VSTR + tt]);
                        lep += (ok ? wr[dy * 3 + dx] : 0.0f) * vv;
                    }
                }
                const float o = acc[t][j] * l4[j] + lep;
                const size_t off = ((size_t)y * 64 + xp) * CCH + ch;
                out[base + off] = o;
            }
        }
    }
}

extern "C" void kernel_launch(void* const* d_in, const int* in_sizes, int n_in,
                              void* d_out, int out_size, void* d_ws, size_t ws_size,
                              hipStream_t stream) {
    const float* qkv   = (const float*)d_in[0];
    const float* wconv = (const float*)d_in[1];
    const float* bconv = (const float*)d_in[2];
    float* outp = (float*)d_out;
    hipLaunchKernelGGL(CSSA_69355131896243_kernel, dim3(256), dim3(512), 0, stream,
                       qkv, wconv, bconv, outp);
}

// Round 3
// 202.279 us; speedup vs baseline: 1.1184x; 1.1184x over previous
//
#include <hip/hip_runtime.h>
#include <stdint.h>

// CSSA: B=32, H=W=64, C=64, heads=4, hd=16, strip windows 64x8 -> 256 windows.
// Block = (window, head): 1024 blocks x 256 thr, ~38 KB LDS -> 4 blocks/CU.
// scores^T = K*Q^T so P's C-layout == K=16 B-frag layout -> PV MFMA directly
// from registers (no LDS bounce). acc^T[d][q] -> f32x4 stores (4 consec ch).
#define KSTR2 20     // K row: 16 ch + 4 pad (40 B, 8B-aligned b64 frags)
#define VSTR  520    // Vt row: 512 tok + 8 pad (1040 B, 16B-aligned)

typedef __attribute__((ext_vector_type(4))) short          short4v;
typedef __attribute__((ext_vector_type(8))) short          short8v;
typedef __attribute__((ext_vector_type(4))) float          f32x4;
typedef __attribute__((ext_vector_type(4))) unsigned short us4;

#define HAVE_MFMA16 __has_builtin(__builtin_amdgcn_mfma_f32_16x16x16bf16_1k)

__device__ __forceinline__ float bf2f(unsigned short u) {
    union { unsigned int i; float f; } x; x.i = ((unsigned int)u) << 16; return x.f;
}
__device__ __forceinline__ unsigned short f2bf(float f) {   // round-half-up
    union { float f; unsigned int u; } x; x.f = f;
    return (unsigned short)((x.u + 0x8000u) >> 16);
}
// pack two f32 -> bf16x2 (lo,hi), round-half-up, 3 VALU
__device__ __forceinline__ unsigned int pk2bf(float lo, float hi) {
    union { float f; unsigned int u; } a, b; a.f = lo; b.f = hi;
    return __builtin_amdgcn_perm(b.u + 0x8000u, a.u + 0x8000u, 0x07060302u);
}

__global__ __launch_bounds__(256, 4)
void CSSA_69355131896243_kernel(const float* __restrict__ qkv,
                                const float* __restrict__ wconv,
                                const float* __restrict__ bconv,
                                float* __restrict__ out)
{
    __shared__ unsigned short Kl[512 * KSTR2];   // 20480 B  K[token][d] bf16
    __shared__ unsigned short Vt[16 * VSTR];     // 16640 B  V^T[d][token] bf16
    __shared__ float Wl[144];                    // this head's 16x9 conv weights
    __shared__ float Bl[16];                     // this head's bias

    const int tid  = threadIdx.x;
    const int wave = tid >> 6, lane = tid & 63, quad = lane >> 4, l15 = lane & 15;

    // block -> (window, head); all 4 heads of a window land on one XCD under
    // both round-robin (%8) and chunked dispatch -> Q/K/V/out lines shared in L2.
    const int bid = blockIdx.x;
    const int win = (bid & 7) * 32 + ((bid >> 3) >> 2);
    const int h   = (bid >> 3) & 3;
    const int b   = win >> 3, wx = win & 7;

    const size_t ONE  = (size_t)32 * 4096 * 64;
    const size_t base = ((size_t)b * 4096 + (size_t)wx * 8) * 64;
    const float* gQ = qkv + base;
    const float* gK = qkv + ONE + base;
    const float* gV = qkv + 2 * ONE + base;

    if (tid < 144) Wl[tid] = wconv[h * 144 + tid];
    if (tid < 16)  Bl[tid] = bconv[h * 16 + tid];

    // ---- stage this head's K (natural) + V (transposed) as bf16 ----
    {
        const int t4 = tid >> 2;        // 64 tokens per round
        const int c4 = tid & 3;         // 4-ch group within head
        for (int r = 0; r < 8; ++r) {
            const int t = r * 64 + t4;
            const size_t goff = (size_t)(t >> 3) * 4096 + (size_t)(t & 7) * 64 + h * 16 + c4 * 4;
            f32x4 kd = *(const f32x4*)(gK + goff);
            f32x4 vd = *(const f32x4*)(gV + goff);
            us4 kb;
            #pragma unroll
            for (int j = 0; j < 4; ++j) kb[j] = f2bf(kd[j]);
            *(us4*)(&Kl[t * KSTR2 + c4 * 4]) = kb;
            #pragma unroll
            for (int j = 0; j < 4; ++j) Vt[(c4 * 4 + j) * VSTR + t] = f2bf(vd[j]);
        }
    }

    // ---- Q prefetch (independent of LDS; overlaps barrier wait) ----
    const float SCL = 0.25f * 1.44269504088896341f;   // scale * log2(e), folded into Q
#if HAVE_MFMA16
    f32x4 qv[8];
    #pragma unroll
    for (int t = 0; t < 8; ++t) {
        const int q = wave * 128 + t * 16 + l15;
        qv[t] = *(const f32x4*)(gQ + (size_t)(q >> 3) * 4096 + (size_t)(q & 7) * 64 + h * 16 + quad * 4);
    }
#else
    f32x4 qv0[8], qv1[8];
    #pragma unroll
    for (int t = 0; t < 8; ++t) {
        const int q = wave * 128 + t * 16 + l15;
        const size_t off = (size_t)(q >> 3) * 4096 + (size_t)(q & 7) * 64 + h * 16 + (quad & 1) * 8;
        qv0[t] = *(const f32x4*)(gQ + off);
        qv1[t] = *(const f32x4*)(gQ + off + 4);
    }
#endif
    __syncthreads();

#if HAVE_MFMA16
    short4v qf[8];   // B[k=d=quad*4+i][n=q=l15], scale folded
    #pragma unroll
    for (int t = 0; t < 8; ++t) {
        union { short4v s; unsigned int u[2]; } p;
        p.u[0] = pk2bf(qv[t][0] * SCL, qv[t][1] * SCL);
        p.u[1] = pk2bf(qv[t][2] * SCL, qv[t][3] * SCL);
        qf[t] = p.s;
    }
#else
    short8v qf[8];
    #pragma unroll
    for (int t = 0; t < 8; ++t) {
        short8v f = (short8v)0;
        if (quad < 2) {
            union { short4v s; unsigned int u[2]; } pa, pb;
            pa.u[0] = pk2bf(qv0[t][0] * SCL, qv0[t][1] * SCL);
            pa.u[1] = pk2bf(qv0[t][2] * SCL, qv0[t][3] * SCL);
            pb.u[0] = pk2bf(qv1[t][0] * SCL, qv1[t][1] * SCL);
            pb.u[1] = pk2bf(qv1[t][2] * SCL, qv1[t][3] * SCL);
            #pragma unroll
            for (int i = 0; i < 4; ++i) { f[i] = pa.s[i]; f[4 + i] = pb.s[i]; }
        }
        qf[t] = f;
    }
#endif

    f32x4 acc[8];
    float lp[8];
    #pragma unroll
    for (int t = 0; t < 8; ++t) { acc[t] = (f32x4)0.0f; lp[t] = 0.0f; }

#if HAVE_MFMA16
    // ---- main loop: 32 chunks x 16 keys; frags double-buffered in regs ----
    short4v kf = *(const short4v*)(&Kl[l15 * KSTR2 + quad * 4]);
    short4v vf = *(const short4v*)(&Vt[l15 * VSTR + quad * 4]);
    for (int c = 0; c < 32; ++c) {
        const int kn = ((c + 1) & 31) * 16;
        short4v kf_n = *(const short4v*)(&Kl[(kn + l15) * KSTR2 + quad * 4]);
        short4v vf_n = *(const short4v*)(&Vt[l15 * VSTR + kn + quad * 4]);
        #pragma unroll
        for (int t = 0; t < 8; ++t) {
            // s^T[key][q]: A=K-frag, B=Q-frag (swapped product)
            f32x4 s = __builtin_amdgcn_mfma_f32_16x16x16bf16_1k(kf, qf[t], (f32x4)0.0f, 0, 0, 0);
            float p0 = __builtin_amdgcn_exp2f(s[0]);
            float p1 = __builtin_amdgcn_exp2f(s[1]);
            float p2 = __builtin_amdgcn_exp2f(s[2]);
            float p3 = __builtin_amdgcn_exp2f(s[3]);
            lp[t] += (p0 + p1) + (p2 + p3);
            union { short4v s4; unsigned int u[2]; } pf;
            pf.u[0] = pk2bf(p0, p1);
            pf.u[1] = pk2bf(p2, p3);
            // acc^T[d][q] += V^T[d][key] * P^T[key][q]; P C-layout == B-frag layout
            acc[t] = __builtin_amdgcn_mfma_f32_16x16x16bf16_1k(vf, pf.s4, acc[t], 0, 0, 0);
        }
        kf = kf_n; vf = vf_n;
    }
#else
    // ---- fallback: 16x16x32, chunk pairs + ds_bpermute C->B transform ----
    const int bidx0 = (((quad & 1) * 2) * 16 + l15) * 4;
    const int bidx1 = bidx0 + 64;
    for (int c = 0; c < 16; ++c) {
        const int k0 = c * 32;
        short8v kfA = (short8v)0, kfB = (short8v)0;
        if (quad < 2) {
            const short4v a0 = *(const short4v*)(&Kl[(k0 + l15) * KSTR2 + quad * 8]);
            const short4v a1 = *(const short4v*)(&Kl[(k0 + l15) * KSTR2 + quad * 8 + 4]);
            const short4v b0 = *(const short4v*)(&Kl[(k0 + 16 + l15) * KSTR2 + quad * 8]);
            const short4v b1 = *(const short4v*)(&Kl[(k0 + 16 + l15) * KSTR2 + quad * 8 + 4]);
            #pragma unroll
            for (int i = 0; i < 4; ++i) { kfA[i] = a0[i]; kfA[4 + i] = a1[i]; kfB[i] = b0[i]; kfB[4 + i] = b1[i]; }
        }
        const short8v vf8 = *(const short8v*)(&Vt[l15 * VSTR + k0 + quad * 8]);
        #pragma unroll
        for (int t = 0; t < 8; ++t) {
            f32x4 s0 = __builtin_amdgcn_mfma_f32_16x16x32_bf16(kfA, qf[t], (f32x4)0.0f, 0, 0, 0);
            f32x4 s1 = __builtin_amdgcn_mfma_f32_16x16x32_bf16(kfB, qf[t], (f32x4)0.0f, 0, 0, 0);
            float e0[4], e1[4];
            #pragma unroll
            for (int j = 0; j < 4; ++j) {
                e0[j] = __builtin_amdgcn_exp2f(s0[j]);
                e1[j] = __builtin_amdgcn_exp2f(s1[j]);
                lp[t] += e0[j] + e1[j];
            }
            const unsigned int a0 = pk2bf(e0[0], e0[1]), a1 = pk2bf(e0[2], e0[3]);
            const unsigned int b0 = pk2bf(e1[0], e1[1]), b1 = pk2bf(e1[2], e1[3]);
            const unsigned int s0u = (quad < 2) ? a0 : b0;
            const unsigned int s1u = (quad < 2) ? a1 : b1;
            union { short8v s8; unsigned int u[4]; } pf;
            pf.u[0] = (unsigned int)__builtin_amdgcn_ds_bpermute(bidx0, (int)s0u);
            pf.u[1] = (unsigned int)__builtin_amdgcn_ds_bpermute(bidx0, (int)s1u);
            pf.u[2] = (unsigned int)__builtin_amdgcn_ds_bpermute(bidx1, (int)s0u);
            pf.u[3] = (unsigned int)__builtin_amdgcn_ds_bpermute(bidx1, (int)s1u);
            acc[t] = __builtin_amdgcn_mfma_f32_16x16x32_bf16(vf8, pf.s8, acc[t], 0, 0, 0);
        }
    }
#endif

    // ---- denominators: reduce per-lane partials across quads ----
    float linv[8];
    #pragma unroll
    for (int t = 0; t < 8; ++t) {
        float v = lp[t];
        v += __shfl_xor(v, 16, 64);
        v += __shfl_xor(v, 32, 64);
        linv[t] = __builtin_amdgcn_rcpf(v);
    }

    // ---- epilogue: LePE from resident V^T, normalize, f32x4 stores ----
    #pragma unroll
    for (int j = 0; j < 4; ++j) {
        const int d = quad * 4 + j;
        float w9[9];
        #pragma unroll
        for (int o = 0; o < 9; ++o) w9[o] = Wl[d * 9 + o];
        const float bs = Bl[d];
        #pragma unroll
        for (int t = 0; t < 8; ++t) {
            const int q = wave * 128 + t * 16 + l15;
            const int y = q >> 3, x = q & 7;
            float lep = bs;
            #pragma unroll
            for (int dy = 0; dy < 3; ++dy) {
                #pragma unroll
                for (int dx = 0; dx < 3; ++dx) {
                    const int yy = y + dy - 1, xx = x + dx - 1;
                    const bool ok = ((unsigned)yy < 64u) && ((unsigned)xx < 8u);
                    const int tt = (q + (dy - 1) * 8 + (dx - 1)) & 511;  // masked if OOB
                    lep += (ok ? w9[dy * 3 + dx] : 0.0f) * bf2f(Vt[d * VSTR + tt]);
                }
            }
            acc[t][j] = acc[t][j] * linv[t] + lep;
        }
    }
    float* gO = out + base;
    #pragma unroll
    for (int t = 0; t < 8; ++t) {
        const int q = wave * 128 + t * 16 + l15;
        *(f32x4*)(gO + (size_t)(q >> 3) * 4096 + (size_t)(q & 7) * 64 + h * 16 + quad * 4) = acc[t];
    }
}

extern "C" void kernel_launch(void* const* d_in, const int* in_sizes, int n_in,
                              void* d_out, int out_size, void* d_ws, size_t ws_size,
                              hipStream_t stream) {
    const float* qkv   = (const float*)d_in[0];
    const float* wconv = (const float*)d_in[1];
    const float* bconv = (const float*)d_in[2];
    float* outp = (float*)d_out;
    hipLaunchKernelGGL(CSSA_69355131896243_kernel, dim3(1024), dim3(256), 0, stream,
                       qkv, wconv, bconv, outp);
}